// Round 27
// baseline (285.750 us; speedup 1.0000x reference)
//
#include <hip/hip_runtime.h>
#include <hip/hip_bf16.h>
#include <math.h>

// Mamba2 fused block, round 27: r26 (274.5us) with k_conv416 extended from
// 2x2 quad to 2x4 OCTET per thread: 4x6 input window shared across 8 pixels
// (3 loads/px vs 4), unpacks shared, weight LDS reads CSE'd across all 8.
// Third application of the r25/r26-verified reuse mechanism. Accumulators
// fully static-indexed (r23 scratch-demotion lesson).

#define BN 4
#define HH 128
#define WWID 128
#define LTOK (HH*WWID)          // 16384
#define NTOK (BN*LTOK)          // 65536
#define DMODEL 192
#define DINNER 384
#define NH 32
#define HD 12
#define DST 16
#define CONVD 416               // D_INNER + 2*16
#define KVCHUNKS 64             // L-chunks per batch for k_kv
#define PM 256                  // k_proj tokens per block
#define TILE_SH 12288           // shorts per B tile (64 ch x 192 k)
#define TILE_BY 24576           // bytes per B tile
#define TROW ((size_t)NTOK*64)  // elements per tile-array (tok-major, 64 ch)
#define YPAD 392                // yz LDS row stride (shorts, 784B)

typedef __hip_bfloat16 bf16;
typedef unsigned int uint32;
typedef unsigned short ushort16;
typedef __attribute__((ext_vector_type(8))) short bf16x8;
typedef __attribute__((ext_vector_type(4))) float f32x4;
typedef __attribute__((ext_vector_type(16))) float f32x16;

__device__ __forceinline__ float bflo(uint32 v){ return __uint_as_float((v & 0xffffu) << 16); }
__device__ __forceinline__ float bfhi(uint32 v){ return __uint_as_float(v & 0xffff0000u); }
__device__ __forceinline__ ushort16 f2bf(float f){
    __hip_bfloat16 h = __float2bfloat16(f);
    return *reinterpret_cast<const ushort16*>(&h);
}
__device__ __forceinline__ float ldbf(const bf16* p){
    return __uint_as_float(((uint32)(*(const ushort16*)p)) << 16);
}
__device__ __forceinline__ float ldbfs(const short* p){
    return __uint_as_float(((uint32)(ushort16)(*p)) << 16);
}
__device__ __forceinline__ float softplusf(float x){
    return (x > 20.f) ? x : log1pf(expf(x));
}
__device__ __forceinline__ float siluf(float x){
    return x / (1.f + expf(-x));
}

union BFPK { short s[8]; bf16x8 v; };

// ---------------------------------------------------------------------------
// k_prep: Win -> Wsw (LDS-linear, XOR-swizzled); Wout -> Wout_sh (B-frag
// order); conv weights -> wtr[9][420].
// ---------------------------------------------------------------------------
__global__ __launch_bounds__(256) void k_prep(
    const float* __restrict__ Win, const float* __restrict__ Wout,
    const float* __restrict__ cw,
    bf16* __restrict__ Wsw, bf16* __restrict__ Wout_sh, float* __restrict__ wtr)
{
    const int i = blockIdx.x*256 + threadIdx.x;
    if (i < 832*DMODEL) {
        const int ch = i / DMODEL, k = i - ch*DMODEL;
        const int nt = ch >> 6, row = ch & 63;
        const int ks = k ^ ((row & 7) << 3);
        Wsw[(size_t)nt*TILE_SH + row*DMODEL + ks] = __float2bfloat16(Win[i]);
    }
    if (i < DMODEL*DINNER) {
        const int m = i / DINNER, k = i - m*DINNER;
        const int ni = m >> 4, mr = m & 15;
        const int ks = k >> 5, kq = (k >> 3) & 3, ii = k & 7;
        const int lane = kq*16 + mr;
        Wout_sh[(size_t)((ni*12 + ks)*64 + lane)*8 + ii] = __float2bfloat16(Wout[i]);
    }
    if (i < CONVD*9) { const int c = i/9, k = i - c*9; wtr[k*420 + c] = cw[i]; }
}

// ---------------------------------------------------------------------------
// k_proj_mfma: zxbcdt = u @ Win^T via 32x32x16 bf16 MFMA (r12 pipeline,
// r13 tiled outputs; r17/r19 form).
// ---------------------------------------------------------------------------
__global__ __launch_bounds__(512) void k_proj_mfma(
    const float* __restrict__ u, const bf16* __restrict__ Wsw,
    const float* __restrict__ dt_b, const float* __restrict__ A_log,
    bf16* __restrict__ z_bf, bf16* __restrict__ xbc_pre, float* __restrict__ dA)
{
    __shared__ __align__(16) short S[3*TILE_SH];   // 72 KB ring

    const int tid = threadIdx.x;
    const int m0 = blockIdx.x * PM;
    const int ntbase = blockIdx.y * 7;             // 0 or 7
    const int ntiles = blockIdx.y ? 6 : 7;
    const int wid = tid >> 6, lane = tid & 63;
    const int fr = lane & 31;
    const int hi = lane >> 5;

    const char* gW = (const char*)Wsw;
    auto GLOAD = [&](int nt, int buf) {
        const char* src = gW + (size_t)nt*TILE_BY + wid*3072 + lane*16;
        char* dst = ((char*)S) + buf*TILE_BY + wid*3072;   // wave-uniform base
        #pragma unroll
        for (int c = 0; c < 3; ++c)
            __builtin_amdgcn_global_load_lds(
                (const __attribute__((address_space(1))) void*)(src + c*1024),
                (__attribute__((address_space(3))) void*)(dst + c*1024), 16, 0, 0);
    };

    GLOAD(ntbase, 0);

    const float db = dt_b[fr];
    const float al = expf(A_log[fr]);
    bf16x8 a[12];
    {
        const float* arow = u + (size_t)(m0 + wid*32 + fr)*DMODEL;
        #pragma unroll
        for (int ks=0;ks<12;++ks) {
            const float4 a0 = *(const float4*)(arow + ks*16 + hi*8);
            const float4 a1 = *(const float4*)(arow + ks*16 + hi*8 + 4);
            BFPK pk;
            pk.s[0]=(short)f2bf(a0.x); pk.s[1]=(short)f2bf(a0.y);
            pk.s[2]=(short)f2bf(a0.z); pk.s[3]=(short)f2bf(a0.w);
            pk.s[4]=(short)f2bf(a1.x); pk.s[5]=(short)f2bf(a1.y);
            pk.s[6]=(short)f2bf(a1.z); pk.s[7]=(short)f2bf(a1.w);
            a[ks] = pk.v;
        }
    }
    asm volatile("s_waitcnt vmcnt(0)" ::: "memory");
    GLOAD(ntbase + 1, 1);
    __builtin_amdgcn_s_barrier();
    __builtin_amdgcn_sched_barrier(0);

    const int kswz = (fr & 7) << 3;

    for (int i = 0; i < ntiles; ++i) {
        const int nt = ntbase + i;
        const short* Sb = &S[(i % 3)*TILE_SH];

        f32x16 acc0, acc1;
        #pragma unroll
        for (int q=0;q<16;++q) { acc0[q]=0.f; acc1[q]=0.f; }

        #pragma unroll
        for (int ks=0;ks<12;++ks) {
            const int kk = (ks*16 + hi*8) ^ kswz;
            const bf16x8 b0 = *(const bf16x8*)&Sb[fr*DMODEL + kk];
            const bf16x8 b1 = *(const bf16x8*)&Sb[(32+fr)*DMODEL + kk];
            acc0 = __builtin_amdgcn_mfma_f32_32x32x16_bf16(a[ks], b0, acc0, 0, 0, 0);
            acc1 = __builtin_amdgcn_mfma_f32_32x32x16_bf16(a[ks], b1, acc1, 0, 0, 0);
        }

        #pragma unroll
        for (int ni=0;ni<2;++ni) {
            const f32x16& ac = ni ? acc1 : acc0;
            const int n0 = nt*64 + ni*32;
            if (n0 < DINNER) {
                bf16* dst = z_bf + (size_t)nt*TROW + (ni*32 + fr);
                #pragma unroll
                for (int r=0;r<16;++r) {
                    const int tok = m0 + wid*32 + (r&3) + 8*(r>>2) + 4*hi;
                    dst[(size_t)tok*64] = __float2bfloat16(ac[r]);
                }
            } else if (n0 < 800) {
                const int loc = n0 - DINNER + fr;
                bf16* dst = xbc_pre + (size_t)(loc>>6)*TROW + (loc & 63);
                #pragma unroll
                for (int r=0;r<16;++r) {
                    const int tok = m0 + wid*32 + (r&3) + 8*(r>>2) + 4*hi;
                    dst[(size_t)tok*64] = __float2bfloat16(ac[r]);
                }
            } else {
                #pragma unroll
                for (int r=0;r<16;++r) {
                    const int tok = m0 + wid*32 + (r&3) + 8*(r>>2) + 4*hi;
                    const float dt = softplusf(ac[r] + db);
                    dA[(size_t)tok*NH + fr] = dt * al;
                }
            }
        }

        if (i + 2 < ntiles) {
            GLOAD(nt + 2, (i + 2) % 3);
            asm volatile("s_waitcnt vmcnt(35)" ::: "memory");
        } else {
            asm volatile("s_waitcnt vmcnt(32)" ::: "memory");
        }
        __builtin_amdgcn_s_barrier();
        __builtin_amdgcn_sched_barrier(0);
    }
}

// ---------------------------------------------------------------------------
// k_tproj: cq_pre[tok][n] = t[tok] . Wtin[784+n], n=0..15. 16 tokens/block.
// ---------------------------------------------------------------------------
__global__ __launch_bounds__(256) void k_tproj(
    const float* __restrict__ t, const float* __restrict__ Wtin, float* __restrict__ cq_pre)
{
    __shared__ float ts[16][196];
    __shared__ float ws[16][196];
    const int tid = threadIdx.x;
    const int tok0 = blockIdx.x * 16;
    #pragma unroll
    for (int i = 0; i < 3; ++i) {
        const int flat = tid + 256*i;
        const int row = flat / 48, c = (flat % 48)*4;
        *(float4*)&ts[row][c] = *(const float4*)(t    + (size_t)(tok0+row)*DMODEL + c);
        *(float4*)&ws[row][c] = *(const float4*)(Wtin + (size_t)(784+row)*DMODEL + c);
    }
    __syncthreads();
    const int tt = tid >> 4, n = tid & 15;
    float s0=0.f,s1=0.f,s2=0.f,s3=0.f;
    #pragma unroll 4
    for (int k = 0; k < DMODEL; k += 4) {
        s0 = fmaf(ts[tt][k+0], ws[n][k+0], s0);
        s1 = fmaf(ts[tt][k+1], ws[n][k+1], s1);
        s2 = fmaf(ts[tt][k+2], ws[n][k+2], s2);
        s3 = fmaf(ts[tt][k+3], ws[n][k+3], s3);
    }
    cq_pre[(size_t)(tok0+tt)*DST + n] = (s0+s1)+(s2+s3);
}

// ---------------------------------------------------------------------------
// k_conv416 (v5, 2x4 octet/thread): depthwise 3x3 SAME conv + bias + SiLU.
// Block = 416 threads = 8 octets x 52 channel-groups -> 64 pixels/block
// (2 rows x 32 cols). bid -> bb=bid>>8, h0=((bid&255)>>2)*2,
// w0=((bid&3)<<5)+pl*4. Shared 4x6 window (24 loads / 8 px = 3/px);
// acc[v][u] tap (dr,dc) valid iff dr-v,dc-u in [-1,1],
// wi=(dr-v+1)*3+(dc-u+1). All acc indices compile-time (full unroll).
// ---------------------------------------------------------------------------
__global__ __launch_bounds__(416) void k_conv416(
    const bf16* __restrict__ in, const float* __restrict__ wtr, const float* __restrict__ cb,
    bf16* __restrict__ out)
{
    __shared__ float ws[9*420];
    __shared__ float bs[416];
    const int tid = threadIdx.x;
    for (int i = tid; i < 9*420; i += 416) ws[i] = wtr[i];
    if (tid < 416) bs[tid] = cb[tid];
    __syncthreads();

    const int pl  = tid / 52;              // octet index 0..7
    const int grp = tid - pl*52;
    const int c0  = grp*8;
    const int bid = blockIdx.x;
    const int bb  = bid >> 8;              // 256 blocks per image (64 x 4)
    const int rem = bid & 255;
    const int h0  = (rem >> 2) << 1;       // even row
    const int w0  = ((rem & 3) << 5) + pl*4;

    const bf16* inT = in + (size_t)(c0 >> 6)*TROW + (c0 & 63);

    float acc[2][4][8];
    {
        const float4 b0 = *(const float4*)&bs[c0];
        const float4 b1 = *(const float4*)&bs[c0+4];
        #pragma unroll
        for (int v2 = 0; v2 < 2; ++v2)
            #pragma unroll
            for (int u = 0; u < 4; ++u) {
                acc[v2][u][0]=b0.x; acc[v2][u][1]=b0.y;
                acc[v2][u][2]=b0.z; acc[v2][u][3]=b0.w;
                acc[v2][u][4]=b1.x; acc[v2][u][5]=b1.y;
                acc[v2][u][6]=b1.z; acc[v2][u][7]=b1.w;
            }
    }

    #pragma unroll
    for (int dr=-1; dr<=2; ++dr) {
        const int rr = h0 + dr;
        if ((unsigned)rr >= (unsigned)HH) continue;
        const int rowb = (bb<<14) + (rr<<7);
        #pragma unroll
        for (int dc=-1; dc<=4; ++dc) {
            const int wc = w0 + dc;
            if ((unsigned)wc >= (unsigned)WWID) continue;
            const uint4 v = *(const uint4*)((const ushort16*)inT + (size_t)(rowb + wc)*64);
            const float x0=bflo(v.x), x1=bfhi(v.x), x2=bflo(v.y), x3=bfhi(v.y);
            const float x4=bflo(v.z), x5=bfhi(v.z), x6=bflo(v.w), x7=bfhi(v.w);
            #pragma unroll
            for (int v2 = 0; v2 < 2; ++v2) {
                const int dh = dr - v2;
                if (dh < -1 || dh > 1) continue;
                #pragma unroll
                for (int u = 0; u < 4; ++u) {
                    const int dw = dc - u;
                    if (dw < -1 || dw > 1) continue;
                    const int wi = (dh+1)*3 + (dw+1);
                    const float4 w0v = *(const float4*)&ws[wi*420 + c0];
                    const float4 w1v = *(const float4*)&ws[wi*420 + c0 + 4];
                    acc[v2][u][0]=fmaf(x0,w0v.x,acc[v2][u][0]);
                    acc[v2][u][1]=fmaf(x1,w0v.y,acc[v2][u][1]);
                    acc[v2][u][2]=fmaf(x2,w0v.z,acc[v2][u][2]);
                    acc[v2][u][3]=fmaf(x3,w0v.w,acc[v2][u][3]);
                    acc[v2][u][4]=fmaf(x4,w1v.x,acc[v2][u][4]);
                    acc[v2][u][5]=fmaf(x5,w1v.y,acc[v2][u][5]);
                    acc[v2][u][6]=fmaf(x6,w1v.z,acc[v2][u][6]);
                    acc[v2][u][7]=fmaf(x7,w1v.w,acc[v2][u][7]);
                }
            }
        }
    }

    const int pix00 = (bb<<14) + (h0<<7) + w0;
    #pragma unroll
    for (int v2 = 0; v2 < 2; ++v2) {
        #pragma unroll
        for (int u = 0; u < 4; ++u) {
            uint4 o;
            o.x = ((uint32)f2bf(siluf(acc[v2][u][1])) << 16) | (uint32)f2bf(siluf(acc[v2][u][0]));
            o.y = ((uint32)f2bf(siluf(acc[v2][u][3])) << 16) | (uint32)f2bf(siluf(acc[v2][u][2]));
            o.z = ((uint32)f2bf(siluf(acc[v2][u][5])) << 16) | (uint32)f2bf(siluf(acc[v2][u][4]));
            o.w = ((uint32)f2bf(siluf(acc[v2][u][7])) << 16) | (uint32)f2bf(siluf(acc[v2][u][6]));
            *(uint4*)((ushort16*)out + (size_t)(pix00 + v2*WWID + u)*CONVD + c0) = o;
        }
    }
}

// ---------------------------------------------------------------------------
// k_conv16: conv for the 16 Cq channels (400..415); bf16 output.
// ---------------------------------------------------------------------------
__global__ __launch_bounds__(256) void k_conv16(
    const float* __restrict__ in, const float* __restrict__ cw, const float* __restrict__ cb,
    bf16* __restrict__ out)
{
    const int idx = blockIdx.x*256 + threadIdx.x;   // NTOK*16
    const int cc = idx & 15;
    const int pix = idx >> 4;
    const int hw = pix & (LTOK-1);
    const int h = hw >> 7, w = hw & 127;
    const int bb = pix >> 14;
    const int c = 400 + cc;

    float wg[9];
    #pragma unroll
    for (int k=0;k<9;++k) wg[k] = cw[c*9+k];
    float a = cb[c];
    #pragma unroll
    for (int dh=-1; dh<=1; ++dh) {
        const int hh = h + dh;
        if ((unsigned)hh >= (unsigned)HH) continue;
        #pragma unroll
        for (int dw=-1; dw<=1; ++dw) {
            const int w2 = w + dw;
            if ((unsigned)w2 >= (unsigned)WWID) continue;
            a = fmaf(in[((size_t)((bb<<14)+(hh<<7)+w2))*16 + cc], wg[(dh+1)*3 + (dw+1)], a);
        }
    }
    out[(size_t)pix*16 + cc] = __float2bfloat16(siluf(a));
}

// ---------------------------------------------------------------------------
// k_kv: partial KV per (batch, 256-token chunk).
// ---------------------------------------------------------------------------
__global__ __launch_bounds__(512) void k_kv(
    const bf16* __restrict__ xbc_post, const float* __restrict__ dA,
    float* __restrict__ partial)
{
    __shared__ short vsb[16][408];
    __shared__ float das[16][32];
    const int tid = threadIdx.x;
    const int b = blockIdx.y;
    const int n = tid & 15;
    const int g = tid >> 4;

    float acc[12];
    #pragma unroll
    for (int j=0;j<12;++j) acc[j]=0.f;

    const int l0base = b*LTOK + blockIdx.x*256;

    for (int it = 0; it < 16; ++it) {
        const int l0 = l0base + it*16;
        for (int i = tid; i < 16*200; i += 512) {
            const int tok = i / 200;
            const int c2 = i - tok*200;
            const uint32 v = *(const uint32*)((const ushort16*)xbc_post
                                + (size_t)(l0+tok)*CONVD + c2*2);
            *(uint32*)&vsb[tok][c2*2] = v;
        }
        {
            const int tok = tid >> 5, h = tid & 31;
            das[tok][h] = dA[(size_t)(l0+tok)*NH + h];
        }
        __syncthreads();

        #pragma unroll
        for (int tok = 0; tok < 16; ++tok) {
            const uint32 bkraw = (uint32)(ushort16)vsb[tok][DINNER + n];
            const float s = __uint_as_float(bkraw << 16) * das[tok][g];
            const uint32* vp = (const uint32*)&vsb[tok][g*12];
            const uint32 w0 = vp[0], w1 = vp[1], w2 = vp[2];
            acc[0]  = fmaf(s, bflo(w0), acc[0]);
            acc[1]  = fmaf(s, bfhi(w0), acc[1]);
            acc[2]  = fmaf(s, bflo(w1), acc[2]);
            acc[3]  = fmaf(s, bfhi(w1), acc[3]);
            acc[4]  = fmaf(s, bflo(w2), acc[4]);
            acc[5]  = fmaf(s, bfhi(w2), acc[5]);
            const uint32* vq = (const uint32*)&vsb[tok][g*12 + 6];
            const uint32 w3 = vq[0], w4 = vq[1], w5 = vq[2];
            acc[6]  = fmaf(s, bflo(w3), acc[6]);
            acc[7]  = fmaf(s, bfhi(w3), acc[7]);
            acc[8]  = fmaf(s, bflo(w4), acc[8]);
            acc[9]  = fmaf(s, bfhi(w4), acc[9]);
            acc[10] = fmaf(s, bflo(w5), acc[10]);
            acc[11] = fmaf(s, bfhi(w5), acc[11]);
        }
        __syncthreads();
    }

    float* dst = partial + ((size_t)(b*KVCHUNKS + blockIdx.x))*6144 + (size_t)tid*12;
    #pragma unroll
    for (int j4=0;j4<3;++j4)
        *(float4*)(dst + j4*4) = make_float4(acc[j4*4], acc[j4*4+1], acc[j4*4+2], acc[j4*4+3]);
}

// ---------------------------------------------------------------------------
// k_kvred: reduce partials AND pre-fragment: kvhl[b][0][hd*16+n] = hi bf16,
// kvhl[b][1][hd*16+n] = lo bf16 (hd = h*12+d).
// ---------------------------------------------------------------------------
__global__ __launch_bounds__(256) void k_kvred(
    const float* __restrict__ partial, bf16* __restrict__ kvhl)
{
    const int idx = blockIdx.x*256 + threadIdx.x;   // 4*6144
    const int b = idx / 6144;
    const int rem = idx - b*6144;
    const int hd = rem >> 4, n = rem & 15;
    const int h = hd / HD, d = hd - h*HD;
    const float* p = partial + (size_t)(b*KVCHUNKS)*6144 + h*192 + n*12 + d;
    float s = 0.f;
    #pragma unroll 4
    for (int c = 0; c < KVCHUNKS; ++c) s += p[(size_t)c*6144];
    const bf16 hi = __float2bfloat16(s);
    const float hif = ldbf(&hi);
    kvhl[((size_t)b*2 + 0)*6144 + rem] = hi;
    kvhl[((size_t)b*2 + 1)*6144 + rem] = __float2bfloat16(s - hif);
}

// ---------------------------------------------------------------------------
// k_ynorm_out (FUSED, r19 form): 64 tokens/block, 4 waves. V tile staged to
// yzs LDS; kv hi/lo fragments read directly from L2-hot kvhl in the MFMA
// loop; register LN; gate by z; out-GEMM from yzs + Wout_sh fragments.
// ---------------------------------------------------------------------------
__global__ __launch_bounds__(256) void k_ynorm_out(
    const bf16* __restrict__ xbc_post, const bf16* __restrict__ cq_bf,
    const bf16* __restrict__ z_bf, const bf16* __restrict__ kvhl,
    const float* __restrict__ Dv, const float* __restrict__ ln_g, const float* __restrict__ ln_b,
    const bf16* __restrict__ Wout_sh, float* __restrict__ out)
{
    __shared__ __align__(16) short yzs[64*YPAD];    // 50.2 KB (V tile, then yz)
    __shared__ float gs[DINNER], bs2[DINNER], ds[DINNER];
    const int tid = threadIdx.x;
    const int token0 = blockIdx.x * 64;
    const int b = token0 >> 14;

    {
        const int row = tid >> 2, seg = tid & 3;    // 64 rows x 4 segs x 96 sh
        const short* src = (const short*)xbc_post + (size_t)(token0+row)*CONVD + seg*96;
        short* dst = &yzs[row*YPAD + seg*96];
        #pragma unroll
        for (int j = 0; j < 12; ++j)
            *(uint4*)(dst + j*8) = *(const uint4*)(src + j*8);
    }

    for (int i = tid; i < DINNER; i += 256) {
        gs[i]  = ln_g[i];
        bs2[i] = ln_b[i];
        ds[i]  = Dv[i/HD];
    }
    __syncthreads();

    const int wid = tid >> 6, lane = tid & 63;
    const int fr = lane & 15, fq = lane >> 4;
    const int tokA = token0 + wid*16;

    const bf16x8 cqf = *(const bf16x8*)((const short*)cq_bf + (size_t)(tokA+fr)*DST + (fq&1)*8);

    const short* kvsrc = (const short*)kvhl + ((size_t)b*2 + (fq >> 1))*6144
                         + (size_t)fr*16 + (fq & 1)*8;   // + t*256 per tile

    f32x4 acc[24];
    #pragma unroll
    for (int t = 0; t < 24; ++t) {
        const bf16x8 bfv = *(const bf16x8*)(kvsrc + t*256);
        f32x4 z4 = (f32x4){0.f,0.f,0.f,0.f};
        acc[t] = __builtin_amdgcn_mfma_f32_16x16x32_bf16(cqf, bfv, z4, 0, 0, 0);
    }

    const int rloc0 = wid*16 + fq*4;       // local row of first token
    const int tokj0 = tokA + fq*4;
    float s[4]  = {0.f,0.f,0.f,0.f};
    float s2[4] = {0.f,0.f,0.f,0.f};
    #pragma unroll
    for (int t = 0; t < 24; ++t) {
        const int hd = t*16 + fr;
        const float dvh = ds[hd];
        #pragma unroll
        for (int j = 0; j < 4; ++j) {
            const float vv = ldbfs(&yzs[(rloc0+j)*YPAD + hd]);
            const float y = fmaf(vv, dvh, acc[t][j]);
            acc[t][j] = y;
            s[j] += y;
            s2[j] = fmaf(y, y, s2[j]);
        }
    }
    #pragma unroll
    for (int j = 0; j < 4; ++j) {
        #pragma unroll
        for (int off = 8; off > 0; off >>= 1) {
            s[j]  += __shfl_xor(s[j],  off, 16);
            s2[j] += __shfl_xor(s2[j], off, 16);
        }
    }
    float mu[4], rs[4];
    #pragma unroll
    for (int j = 0; j < 4; ++j) {
        mu[j] = s[j] * (1.f/384.f);
        const float var = s2[j]*(1.f/384.f) - mu[j]*mu[j];
        rs[j] = rsqrtf(var + 1e-5f);
    }

    #pragma unroll
    for (int t = 0; t < 24; ++t) {
        const int hd = t*16 + fr;
        const float g = gs[hd], be = bs2[hd];
        const bf16* zsrc = z_bf + (size_t)(hd>>6)*TROW + (hd & 63);
        #pragma unroll
        for (int j = 0; j < 4; ++j) {
            const int tok = tokj0 + j;
            const float yn = fmaf((acc[t][j] - mu[j])*rs[j], g, be);
            const float zv = ldbf(zsrc + (size_t)tok*64);
            yzs[(rloc0+j)*YPAD + hd] = (short)f2bf(yn*zv);
        }
    }

    const short* yrow = &yzs[(wid*16 + fr)*YPAD];
    bf16x8 af[12];
    #pragma unroll
    for (int ks = 0; ks < 12; ++ks)
        af[ks] = *(const bf16x8*)(yrow + ks*32 + fq*8);

    f32x4 oacc[12];
    #pragma unroll
    for (int ni = 0; ni < 12; ++ni) oacc[ni] = (f32x4){0.f,0.f,0.f,0.f};

    #pragma unroll
    for (int ks = 0; ks < 12; ++ks) {
        #pragma unroll
        for (int ni = 0; ni < 12; ++ni) {
            const bf16x8 bw = *(const bf16x8*)((const short*)Wout_sh
                                + (size_t)((ni*12 + ks)*64 + lane)*8);
            oacc[ni] = __builtin_amdgcn_mfma_f32_16x16x32_bf16(af[ks], bw, oacc[ni], 0, 0, 0);
        }
    }

    #pragma unroll
    for (int ni = 0; ni < 12; ++ni) {
        const int n = ni*16 + fr;
        #pragma unroll
        for (int r = 0; r < 4; ++r)
            out[(size_t)(tokj0 + r)*DMODEL + n] = oacc[ni][r];
    }
}

// ---------------------------------------------------------------------------
extern "C" void kernel_launch(void* const* d_in, const int* in_sizes, int n_in,
                              void* d_out, int out_size, void* d_ws, size_t ws_size,
                              hipStream_t stream)
{
    const float* u      = (const float*)d_in[0];
    const float* t      = (const float*)d_in[1];
    const float* Win    = (const float*)d_in[2];
    const float* Wtin   = (const float*)d_in[3];
    const float* conv_w = (const float*)d_in[4];
    const float* conv_b = (const float*)d_in[5];
    const float* dt_b   = (const float*)d_in[6];
    const float* A_log  = (const float*)d_in[7];
    const float* Dv     = (const float*)d_in[8];
    const float* ln_g   = (const float*)d_in[9];
    const float* ln_bt  = (const float*)d_in[10];
    const float* W_out  = (const float*)d_in[11];
    float* out = (float*)d_out;

    char* p = (char*)d_ws;
    bf16* z_bf     = (bf16*)p;  p += (size_t)6*TROW*2;        // 50.3 MB (tiled)
    bf16* xbc_pre  = (bf16*)p;  p += (size_t)7*TROW*2;        // 58.7 MB (tiled; reused as kv partials)
    bf16* xbc_post = (bf16*)p;  p += (size_t)NTOK*CONVD*2;    // 54.5 MB
    float* cq_pre  = (float*)p; p += (size_t)NTOK*DST*4;      //  4.2 MB
    bf16* cq_bf    = (bf16*)p;  p += (size_t)NTOK*DST*2;      //  2.1 MB
    float* dA      = (float*)p; p += (size_t)NTOK*NH*4;       //  8.4 MB
    bf16* kvhl     = (bf16*)p;  p += (size_t)BN*2*6144*2;     //  98 KB
    bf16* Wsw      = (bf16*)p;  p += (size_t)832*DMODEL*2;    // 320 KB (swizzled frags)
    bf16* Wout_sh  = (bf16*)p;  p += (size_t)DMODEL*DINNER*2; // 148 KB (out B-frags)
    float* wtr     = (float*)p; p += (size_t)9*420*4;         // 15.1 KB

    float* kv_part = (float*)xbc_pre;   // xbc_pre dead after k_conv416

    k_prep<<<624, 256, 0, stream>>>(Win, W_out, conv_w, Wsw, Wout_sh, wtr);
    k_proj_mfma<<<dim3(NTOK/PM, 2), 512, 0, stream>>>(u, Wsw, dt_b, A_log, z_bf, xbc_pre, dA);
    k_tproj<<<NTOK/16, 256, 0, stream>>>(t, Wtin, cq_pre);
    k_conv416<<<NTOK/64, 416, 0, stream>>>(xbc_pre, wtr, conv_b, xbc_post);
    k_conv16<<<NTOK*16/256, 256, 0, stream>>>(cq_pre, conv_w, conv_b, cq_bf);
    k_kv<<<dim3(KVCHUNKS, BN), 512, 0, stream>>>(xbc_post, dA, kv_part);
    k_kvred<<<BN*6144/256, 256, 0, stream>>>(kv_part, kvhl);
    k_ynorm_out<<<NTOK/64, 256, 0, stream>>>(xbc_post, cq_bf, z_bf, kvhl,
                                             Dv, ln_g, ln_bt, Wout_sh, out);
}

// Round 28
// 273.656 us; speedup vs baseline: 1.0442x; 1.0442x over previous
//
#include <hip/hip_runtime.h>
#include <hip/hip_bf16.h>
#include <math.h>

// Mamba2 fused block, round 28: revert to round 26 exactly (verified best,
// 274.5us). r27's 2x4 octet overshot the register/occupancy sweet spot
// (+11us); the 2x2 quad is the optimum of the conv reuse curve.
// Pipeline: k_prep -> k_proj_mfma -> k_tproj -> k_conv416(2x2 quad) ->
// k_conv16 -> k_kv -> k_kvred -> k_ynorm_out (fused LN+gate+out-GEMM).

#define BN 4
#define HH 128
#define WWID 128
#define LTOK (HH*WWID)          // 16384
#define NTOK (BN*LTOK)          // 65536
#define DMODEL 192
#define DINNER 384
#define NH 32
#define HD 12
#define DST 16
#define CONVD 416               // D_INNER + 2*16
#define KVCHUNKS 64             // L-chunks per batch for k_kv
#define PM 256                  // k_proj tokens per block
#define TILE_SH 12288           // shorts per B tile (64 ch x 192 k)
#define TILE_BY 24576           // bytes per B tile
#define TROW ((size_t)NTOK*64)  // elements per tile-array (tok-major, 64 ch)
#define YPAD 392                // yz LDS row stride (shorts, 784B)

typedef __hip_bfloat16 bf16;
typedef unsigned int uint32;
typedef unsigned short ushort16;
typedef __attribute__((ext_vector_type(8))) short bf16x8;
typedef __attribute__((ext_vector_type(4))) float f32x4;
typedef __attribute__((ext_vector_type(16))) float f32x16;

__device__ __forceinline__ float bflo(uint32 v){ return __uint_as_float((v & 0xffffu) << 16); }
__device__ __forceinline__ float bfhi(uint32 v){ return __uint_as_float(v & 0xffff0000u); }
__device__ __forceinline__ ushort16 f2bf(float f){
    __hip_bfloat16 h = __float2bfloat16(f);
    return *reinterpret_cast<const ushort16*>(&h);
}
__device__ __forceinline__ float ldbf(const bf16* p){
    return __uint_as_float(((uint32)(*(const ushort16*)p)) << 16);
}
__device__ __forceinline__ float ldbfs(const short* p){
    return __uint_as_float(((uint32)(ushort16)(*p)) << 16);
}
__device__ __forceinline__ float softplusf(float x){
    return (x > 20.f) ? x : log1pf(expf(x));
}
__device__ __forceinline__ float siluf(float x){
    return x / (1.f + expf(-x));
}

union BFPK { short s[8]; bf16x8 v; };

// ---------------------------------------------------------------------------
// k_prep: Win -> Wsw (LDS-linear, XOR-swizzled); Wout -> Wout_sh (B-frag
// order); conv weights -> wtr[9][420].
// ---------------------------------------------------------------------------
__global__ __launch_bounds__(256) void k_prep(
    const float* __restrict__ Win, const float* __restrict__ Wout,
    const float* __restrict__ cw,
    bf16* __restrict__ Wsw, bf16* __restrict__ Wout_sh, float* __restrict__ wtr)
{
    const int i = blockIdx.x*256 + threadIdx.x;
    if (i < 832*DMODEL) {
        const int ch = i / DMODEL, k = i - ch*DMODEL;
        const int nt = ch >> 6, row = ch & 63;
        const int ks = k ^ ((row & 7) << 3);
        Wsw[(size_t)nt*TILE_SH + row*DMODEL + ks] = __float2bfloat16(Win[i]);
    }
    if (i < DMODEL*DINNER) {
        const int m = i / DINNER, k = i - m*DINNER;
        const int ni = m >> 4, mr = m & 15;
        const int ks = k >> 5, kq = (k >> 3) & 3, ii = k & 7;
        const int lane = kq*16 + mr;
        Wout_sh[(size_t)((ni*12 + ks)*64 + lane)*8 + ii] = __float2bfloat16(Wout[i]);
    }
    if (i < CONVD*9) { const int c = i/9, k = i - c*9; wtr[k*420 + c] = cw[i]; }
}

// ---------------------------------------------------------------------------
// k_proj_mfma: zxbcdt = u @ Win^T via 32x32x16 bf16 MFMA (r12 pipeline,
// r13 tiled outputs; r17/r19 form).
// ---------------------------------------------------------------------------
__global__ __launch_bounds__(512) void k_proj_mfma(
    const float* __restrict__ u, const bf16* __restrict__ Wsw,
    const float* __restrict__ dt_b, const float* __restrict__ A_log,
    bf16* __restrict__ z_bf, bf16* __restrict__ xbc_pre, float* __restrict__ dA)
{
    __shared__ __align__(16) short S[3*TILE_SH];   // 72 KB ring

    const int tid = threadIdx.x;
    const int m0 = blockIdx.x * PM;
    const int ntbase = blockIdx.y * 7;             // 0 or 7
    const int ntiles = blockIdx.y ? 6 : 7;
    const int wid = tid >> 6, lane = tid & 63;
    const int fr = lane & 31;
    const int hi = lane >> 5;

    const char* gW = (const char*)Wsw;
    auto GLOAD = [&](int nt, int buf) {
        const char* src = gW + (size_t)nt*TILE_BY + wid*3072 + lane*16;
        char* dst = ((char*)S) + buf*TILE_BY + wid*3072;   // wave-uniform base
        #pragma unroll
        for (int c = 0; c < 3; ++c)
            __builtin_amdgcn_global_load_lds(
                (const __attribute__((address_space(1))) void*)(src + c*1024),
                (__attribute__((address_space(3))) void*)(dst + c*1024), 16, 0, 0);
    };

    GLOAD(ntbase, 0);

    const float db = dt_b[fr];
    const float al = expf(A_log[fr]);
    bf16x8 a[12];
    {
        const float* arow = u + (size_t)(m0 + wid*32 + fr)*DMODEL;
        #pragma unroll
        for (int ks=0;ks<12;++ks) {
            const float4 a0 = *(const float4*)(arow + ks*16 + hi*8);
            const float4 a1 = *(const float4*)(arow + ks*16 + hi*8 + 4);
            BFPK pk;
            pk.s[0]=(short)f2bf(a0.x); pk.s[1]=(short)f2bf(a0.y);
            pk.s[2]=(short)f2bf(a0.z); pk.s[3]=(short)f2bf(a0.w);
            pk.s[4]=(short)f2bf(a1.x); pk.s[5]=(short)f2bf(a1.y);
            pk.s[6]=(short)f2bf(a1.z); pk.s[7]=(short)f2bf(a1.w);
            a[ks] = pk.v;
        }
    }
    asm volatile("s_waitcnt vmcnt(0)" ::: "memory");
    GLOAD(ntbase + 1, 1);
    __builtin_amdgcn_s_barrier();
    __builtin_amdgcn_sched_barrier(0);

    const int kswz = (fr & 7) << 3;

    for (int i = 0; i < ntiles; ++i) {
        const int nt = ntbase + i;
        const short* Sb = &S[(i % 3)*TILE_SH];

        f32x16 acc0, acc1;
        #pragma unroll
        for (int q=0;q<16;++q) { acc0[q]=0.f; acc1[q]=0.f; }

        #pragma unroll
        for (int ks=0;ks<12;++ks) {
            const int kk = (ks*16 + hi*8) ^ kswz;
            const bf16x8 b0 = *(const bf16x8*)&Sb[fr*DMODEL + kk];
            const bf16x8 b1 = *(const bf16x8*)&Sb[(32+fr)*DMODEL + kk];
            acc0 = __builtin_amdgcn_mfma_f32_32x32x16_bf16(a[ks], b0, acc0, 0, 0, 0);
            acc1 = __builtin_amdgcn_mfma_f32_32x32x16_bf16(a[ks], b1, acc1, 0, 0, 0);
        }

        #pragma unroll
        for (int ni=0;ni<2;++ni) {
            const f32x16& ac = ni ? acc1 : acc0;
            const int n0 = nt*64 + ni*32;
            if (n0 < DINNER) {
                bf16* dst = z_bf + (size_t)nt*TROW + (ni*32 + fr);
                #pragma unroll
                for (int r=0;r<16;++r) {
                    const int tok = m0 + wid*32 + (r&3) + 8*(r>>2) + 4*hi;
                    dst[(size_t)tok*64] = __float2bfloat16(ac[r]);
                }
            } else if (n0 < 800) {
                const int loc = n0 - DINNER + fr;
                bf16* dst = xbc_pre + (size_t)(loc>>6)*TROW + (loc & 63);
                #pragma unroll
                for (int r=0;r<16;++r) {
                    const int tok = m0 + wid*32 + (r&3) + 8*(r>>2) + 4*hi;
                    dst[(size_t)tok*64] = __float2bfloat16(ac[r]);
                }
            } else {
                #pragma unroll
                for (int r=0;r<16;++r) {
                    const int tok = m0 + wid*32 + (r&3) + 8*(r>>2) + 4*hi;
                    const float dt = softplusf(ac[r] + db);
                    dA[(size_t)tok*NH + fr] = dt * al;
                }
            }
        }

        if (i + 2 < ntiles) {
            GLOAD(nt + 2, (i + 2) % 3);
            asm volatile("s_waitcnt vmcnt(35)" ::: "memory");
        } else {
            asm volatile("s_waitcnt vmcnt(32)" ::: "memory");
        }
        __builtin_amdgcn_s_barrier();
        __builtin_amdgcn_sched_barrier(0);
    }
}

// ---------------------------------------------------------------------------
// k_tproj: cq_pre[tok][n] = t[tok] . Wtin[784+n], n=0..15. 16 tokens/block.
// ---------------------------------------------------------------------------
__global__ __launch_bounds__(256) void k_tproj(
    const float* __restrict__ t, const float* __restrict__ Wtin, float* __restrict__ cq_pre)
{
    __shared__ float ts[16][196];
    __shared__ float ws[16][196];
    const int tid = threadIdx.x;
    const int tok0 = blockIdx.x * 16;
    #pragma unroll
    for (int i = 0; i < 3; ++i) {
        const int flat = tid + 256*i;
        const int row = flat / 48, c = (flat % 48)*4;
        *(float4*)&ts[row][c] = *(const float4*)(t    + (size_t)(tok0+row)*DMODEL + c);
        *(float4*)&ws[row][c] = *(const float4*)(Wtin + (size_t)(784+row)*DMODEL + c);
    }
    __syncthreads();
    const int tt = tid >> 4, n = tid & 15;
    float s0=0.f,s1=0.f,s2=0.f,s3=0.f;
    #pragma unroll 4
    for (int k = 0; k < DMODEL; k += 4) {
        s0 = fmaf(ts[tt][k+0], ws[n][k+0], s0);
        s1 = fmaf(ts[tt][k+1], ws[n][k+1], s1);
        s2 = fmaf(ts[tt][k+2], ws[n][k+2], s2);
        s3 = fmaf(ts[tt][k+3], ws[n][k+3], s3);
    }
    cq_pre[(size_t)(tok0+tt)*DST + n] = (s0+s1)+(s2+s3);
}

// ---------------------------------------------------------------------------
// k_conv416 (2x2 quad/thread, r26 form): depthwise 3x3 SAME conv+bias+SiLU.
// Block = 416 threads = 8 quads x 52 channel-groups -> 32 pixels/block
// (2 rows x 16 cols). bid -> bb=bid>>9, h0=((bid&511)>>3)*2,
// w0=((bid&7)<<4)+pl*2. Shared 4x4 window; acc_{v,u} tap (dr,dc) valid iff
// dr-v,dc-u in [-1,1], wi=(dr-v+1)*3+(dc-u+1).
// ---------------------------------------------------------------------------
__global__ __launch_bounds__(416) void k_conv416(
    const bf16* __restrict__ in, const float* __restrict__ wtr, const float* __restrict__ cb,
    bf16* __restrict__ out)
{
    __shared__ float ws[9*420];
    __shared__ float bs[416];
    const int tid = threadIdx.x;
    for (int i = tid; i < 9*420; i += 416) ws[i] = wtr[i];
    if (tid < 416) bs[tid] = cb[tid];
    __syncthreads();

    const int pl  = tid / 52;              // quad index 0..7
    const int grp = tid - pl*52;
    const int c0  = grp*8;
    const int bid = blockIdx.x;
    const int bb  = bid >> 9;              // 512 blocks per image (64 x 8)
    const int rem = bid & 511;
    const int h0  = (rem >> 3) << 1;       // even row
    const int w0  = ((rem & 7) << 4) + pl*2;

    const bf16* inT = in + (size_t)(c0 >> 6)*TROW + (c0 & 63);

    float a00[8], a01[8], a10[8], a11[8];
    {
        const float4 b0 = *(const float4*)&bs[c0];
        const float4 b1 = *(const float4*)&bs[c0+4];
        a00[0]=b0.x; a00[1]=b0.y; a00[2]=b0.z; a00[3]=b0.w;
        a00[4]=b1.x; a00[5]=b1.y; a00[6]=b1.z; a00[7]=b1.w;
        #pragma unroll
        for (int j=0;j<8;++j) { a01[j]=a00[j]; a10[j]=a00[j]; a11[j]=a00[j]; }
    }

    #pragma unroll
    for (int dr=-1; dr<=2; ++dr) {
        const int rr = h0 + dr;
        if ((unsigned)rr >= (unsigned)HH) continue;
        const int rowb = (bb<<14) + (rr<<7);
        #pragma unroll
        for (int dc=-1; dc<=2; ++dc) {
            const int wc = w0 + dc;
            if ((unsigned)wc >= (unsigned)WWID) continue;
            const uint4 v = *(const uint4*)((const ushort16*)inT + (size_t)(rowb + wc)*64);
            const float x0=bflo(v.x), x1=bfhi(v.x), x2=bflo(v.y), x3=bfhi(v.y);
            const float x4=bflo(v.z), x5=bfhi(v.z), x6=bflo(v.w), x7=bfhi(v.w);
            if (dr <= 1) {
                if (dc <= 1) {                     // a00: dh=dr, dw=dc
                    const int wi = (dr+1)*3 + (dc+1);
                    const float4 w0v = *(const float4*)&ws[wi*420 + c0];
                    const float4 w1v = *(const float4*)&ws[wi*420 + c0 + 4];
                    a00[0]=fmaf(x0,w0v.x,a00[0]); a00[1]=fmaf(x1,w0v.y,a00[1]);
                    a00[2]=fmaf(x2,w0v.z,a00[2]); a00[3]=fmaf(x3,w0v.w,a00[3]);
                    a00[4]=fmaf(x4,w1v.x,a00[4]); a00[5]=fmaf(x5,w1v.y,a00[5]);
                    a00[6]=fmaf(x6,w1v.z,a00[6]); a00[7]=fmaf(x7,w1v.w,a00[7]);
                }
                if (dc >= 0) {                     // a01: dh=dr, dw=dc-1
                    const int wi = (dr+1)*3 + dc;
                    const float4 w0v = *(const float4*)&ws[wi*420 + c0];
                    const float4 w1v = *(const float4*)&ws[wi*420 + c0 + 4];
                    a01[0]=fmaf(x0,w0v.x,a01[0]); a01[1]=fmaf(x1,w0v.y,a01[1]);
                    a01[2]=fmaf(x2,w0v.z,a01[2]); a01[3]=fmaf(x3,w0v.w,a01[3]);
                    a01[4]=fmaf(x4,w1v.x,a01[4]); a01[5]=fmaf(x5,w1v.y,a01[5]);
                    a01[6]=fmaf(x6,w1v.z,a01[6]); a01[7]=fmaf(x7,w1v.w,a01[7]);
                }
            }
            if (dr >= 0) {
                if (dc <= 1) {                     // a10: dh=dr-1, dw=dc
                    const int wi = dr*3 + (dc+1);
                    const float4 w0v = *(const float4*)&ws[wi*420 + c0];
                    const float4 w1v = *(const float4*)&ws[wi*420 + c0 + 4];
                    a10[0]=fmaf(x0,w0v.x,a10[0]); a10[1]=fmaf(x1,w0v.y,a10[1]);
                    a10[2]=fmaf(x2,w0v.z,a10[2]); a10[3]=fmaf(x3,w0v.w,a10[3]);
                    a10[4]=fmaf(x4,w1v.x,a10[4]); a10[5]=fmaf(x5,w1v.y,a10[5]);
                    a10[6]=fmaf(x6,w1v.z,a10[6]); a10[7]=fmaf(x7,w1v.w,a10[7]);
                }
                if (dc >= 0) {                     // a11: dh=dr-1, dw=dc-1
                    const int wi = dr*3 + dc;
                    const float4 w0v = *(const float4*)&ws[wi*420 + c0];
                    const float4 w1v = *(const float4*)&ws[wi*420 + c0 + 4];
                    a11[0]=fmaf(x0,w0v.x,a11[0]); a11[1]=fmaf(x1,w0v.y,a11[1]);
                    a11[2]=fmaf(x2,w0v.z,a11[2]); a11[3]=fmaf(x3,w0v.w,a11[3]);
                    a11[4]=fmaf(x4,w1v.x,a11[4]); a11[5]=fmaf(x5,w1v.y,a11[5]);
                    a11[6]=fmaf(x6,w1v.z,a11[6]); a11[7]=fmaf(x7,w1v.w,a11[7]);
                }
            }
        }
    }

    const int pix00 = (bb<<14) + (h0<<7) + w0;
    {
        uint4 o;
        o.x = ((uint32)f2bf(siluf(a00[1])) << 16) | (uint32)f2bf(siluf(a00[0]));
        o.y = ((uint32)f2bf(siluf(a00[3])) << 16) | (uint32)f2bf(siluf(a00[2]));
        o.z = ((uint32)f2bf(siluf(a00[5])) << 16) | (uint32)f2bf(siluf(a00[4]));
        o.w = ((uint32)f2bf(siluf(a00[7])) << 16) | (uint32)f2bf(siluf(a00[6]));
        *(uint4*)((ushort16*)out + (size_t)pix00*CONVD + c0) = o;
    }
    {
        uint4 o;
        o.x = ((uint32)f2bf(siluf(a01[1])) << 16) | (uint32)f2bf(siluf(a01[0]));
        o.y = ((uint32)f2bf(siluf(a01[3])) << 16) | (uint32)f2bf(siluf(a01[2]));
        o.z = ((uint32)f2bf(siluf(a01[5])) << 16) | (uint32)f2bf(siluf(a01[4]));
        o.w = ((uint32)f2bf(siluf(a01[7])) << 16) | (uint32)f2bf(siluf(a01[6]));
        *(uint4*)((ushort16*)out + (size_t)(pix00+1)*CONVD + c0) = o;
    }
    {
        uint4 o;
        o.x = ((uint32)f2bf(siluf(a10[1])) << 16) | (uint32)f2bf(siluf(a10[0]));
        o.y = ((uint32)f2bf(siluf(a10[3])) << 16) | (uint32)f2bf(siluf(a10[2]));
        o.z = ((uint32)f2bf(siluf(a10[5])) << 16) | (uint32)f2bf(siluf(a10[4]));
        o.w = ((uint32)f2bf(siluf(a10[7])) << 16) | (uint32)f2bf(siluf(a10[6]));
        *(uint4*)((ushort16*)out + (size_t)(pix00+WWID)*CONVD + c0) = o;
    }
    {
        uint4 o;
        o.x = ((uint32)f2bf(siluf(a11[1])) << 16) | (uint32)f2bf(siluf(a11[0]));
        o.y = ((uint32)f2bf(siluf(a11[3])) << 16) | (uint32)f2bf(siluf(a11[2]));
        o.z = ((uint32)f2bf(siluf(a11[5])) << 16) | (uint32)f2bf(siluf(a11[4]));
        o.w = ((uint32)f2bf(siluf(a11[7])) << 16) | (uint32)f2bf(siluf(a11[6]));
        *(uint4*)((ushort16*)out + (size_t)(pix00+WWID+1)*CONVD + c0) = o;
    }
}

// ---------------------------------------------------------------------------
// k_conv16: conv for the 16 Cq channels (400..415); bf16 output.
// ---------------------------------------------------------------------------
__global__ __launch_bounds__(256) void k_conv16(
    const float* __restrict__ in, const float* __restrict__ cw, const float* __restrict__ cb,
    bf16* __restrict__ out)
{
    const int idx = blockIdx.x*256 + threadIdx.x;   // NTOK*16
    const int cc = idx & 15;
    const int pix = idx >> 4;
    const int hw = pix & (LTOK-1);
    const int h = hw >> 7, w = hw & 127;
    const int bb = pix >> 14;
    const int c = 400 + cc;

    float wg[9];
    #pragma unroll
    for (int k=0;k<9;++k) wg[k] = cw[c*9+k];
    float a = cb[c];
    #pragma unroll
    for (int dh=-1; dh<=1; ++dh) {
        const int hh = h + dh;
        if ((unsigned)hh >= (unsigned)HH) continue;
        #pragma unroll
        for (int dw=-1; dw<=1; ++dw) {
            const int w2 = w + dw;
            if ((unsigned)w2 >= (unsigned)WWID) continue;
            a = fmaf(in[((size_t)((bb<<14)+(hh<<7)+w2))*16 + cc], wg[(dh+1)*3 + (dw+1)], a);
        }
    }
    out[(size_t)pix*16 + cc] = __float2bfloat16(siluf(a));
}

// ---------------------------------------------------------------------------
// k_kv: partial KV per (batch, 256-token chunk).
// ---------------------------------------------------------------------------
__global__ __launch_bounds__(512) void k_kv(
    const bf16* __restrict__ xbc_post, const float* __restrict__ dA,
    float* __restrict__ partial)
{
    __shared__ short vsb[16][408];
    __shared__ float das[16][32];
    const int tid = threadIdx.x;
    const int b = blockIdx.y;
    const int n = tid & 15;
    const int g = tid >> 4;

    float acc[12];
    #pragma unroll
    for (int j=0;j<12;++j) acc[j]=0.f;

    const int l0base = b*LTOK + blockIdx.x*256;

    for (int it = 0; it < 16; ++it) {
        const int l0 = l0base + it*16;
        for (int i = tid; i < 16*200; i += 512) {
            const int tok = i / 200;
            const int c2 = i - tok*200;
            const uint32 v = *(const uint32*)((const ushort16*)xbc_post
                                + (size_t)(l0+tok)*CONVD + c2*2);
            *(uint32*)&vsb[tok][c2*2] = v;
        }
        {
            const int tok = tid >> 5, h = tid & 31;
            das[tok][h] = dA[(size_t)(l0+tok)*NH + h];
        }
        __syncthreads();

        #pragma unroll
        for (int tok = 0; tok < 16; ++tok) {
            const uint32 bkraw = (uint32)(ushort16)vsb[tok][DINNER + n];
            const float s = __uint_as_float(bkraw << 16) * das[tok][g];
            const uint32* vp = (const uint32*)&vsb[tok][g*12];
            const uint32 w0 = vp[0], w1 = vp[1], w2 = vp[2];
            acc[0]  = fmaf(s, bflo(w0), acc[0]);
            acc[1]  = fmaf(s, bfhi(w0), acc[1]);
            acc[2]  = fmaf(s, bflo(w1), acc[2]);
            acc[3]  = fmaf(s, bfhi(w1), acc[3]);
            acc[4]  = fmaf(s, bflo(w2), acc[4]);
            acc[5]  = fmaf(s, bfhi(w2), acc[5]);
            const uint32* vq = (const uint32*)&vsb[tok][g*12 + 6];
            const uint32 w3 = vq[0], w4 = vq[1], w5 = vq[2];
            acc[6]  = fmaf(s, bflo(w3), acc[6]);
            acc[7]  = fmaf(s, bfhi(w3), acc[7]);
            acc[8]  = fmaf(s, bflo(w4), acc[8]);
            acc[9]  = fmaf(s, bfhi(w4), acc[9]);
            acc[10] = fmaf(s, bflo(w5), acc[10]);
            acc[11] = fmaf(s, bfhi(w5), acc[11]);
        }
        __syncthreads();
    }

    float* dst = partial + ((size_t)(b*KVCHUNKS + blockIdx.x))*6144 + (size_t)tid*12;
    #pragma unroll
    for (int j4=0;j4<3;++j4)
        *(float4*)(dst + j4*4) = make_float4(acc[j4*4], acc[j4*4+1], acc[j4*4+2], acc[j4*4+3]);
}

// ---------------------------------------------------------------------------
// k_kvred: reduce partials AND pre-fragment: kvhl[b][0][hd*16+n] = hi bf16,
// kvhl[b][1][hd*16+n] = lo bf16 (hd = h*12+d).
// ---------------------------------------------------------------------------
__global__ __launch_bounds__(256) void k_kvred(
    const float* __restrict__ partial, bf16* __restrict__ kvhl)
{
    const int idx = blockIdx.x*256 + threadIdx.x;   // 4*6144
    const int b = idx / 6144;
    const int rem = idx - b*6144;
    const int hd = rem >> 4, n = rem & 15;
    const int h = hd / HD, d = hd - h*HD;
    const float* p = partial + (size_t)(b*KVCHUNKS)*6144 + h*192 + n*12 + d;
    float s = 0.f;
    #pragma unroll 4
    for (int c = 0; c < KVCHUNKS; ++c) s += p[(size_t)c*6144];
    const bf16 hi = __float2bfloat16(s);
    const float hif = ldbf(&hi);
    kvhl[((size_t)b*2 + 0)*6144 + rem] = hi;
    kvhl[((size_t)b*2 + 1)*6144 + rem] = __float2bfloat16(s - hif);
}

// ---------------------------------------------------------------------------
// k_ynorm_out (FUSED, r19 form): 64 tokens/block, 4 waves. V tile staged to
// yzs LDS; kv hi/lo fragments read directly from L2-hot kvhl in the MFMA
// loop; register LN; gate by z; out-GEMM from yzs + Wout_sh fragments.
// ---------------------------------------------------------------------------
__global__ __launch_bounds__(256) void k_ynorm_out(
    const bf16* __restrict__ xbc_post, const bf16* __restrict__ cq_bf,
    const bf16* __restrict__ z_bf, const bf16* __restrict__ kvhl,
    const float* __restrict__ Dv, const float* __restrict__ ln_g, const float* __restrict__ ln_b,
    const bf16* __restrict__ Wout_sh, float* __restrict__ out)
{
    __shared__ __align__(16) short yzs[64*YPAD];    // 50.2 KB (V tile, then yz)
    __shared__ float gs[DINNER], bs2[DINNER], ds[DINNER];
    const int tid = threadIdx.x;
    const int token0 = blockIdx.x * 64;
    const int b = token0 >> 14;

    {
        const int row = tid >> 2, seg = tid & 3;    // 64 rows x 4 segs x 96 sh
        const short* src = (const short*)xbc_post + (size_t)(token0+row)*CONVD + seg*96;
        short* dst = &yzs[row*YPAD + seg*96];
        #pragma unroll
        for (int j = 0; j < 12; ++j)
            *(uint4*)(dst + j*8) = *(const uint4*)(src + j*8);
    }

    for (int i = tid; i < DINNER; i += 256) {
        gs[i]  = ln_g[i];
        bs2[i] = ln_b[i];
        ds[i]  = Dv[i/HD];
    }
    __syncthreads();

    const int wid = tid >> 6, lane = tid & 63;
    const int fr = lane & 15, fq = lane >> 4;
    const int tokA = token0 + wid*16;

    const bf16x8 cqf = *(const bf16x8*)((const short*)cq_bf + (size_t)(tokA+fr)*DST + (fq&1)*8);

    const short* kvsrc = (const short*)kvhl + ((size_t)b*2 + (fq >> 1))*6144
                         + (size_t)fr*16 + (fq & 1)*8;   // + t*256 per tile

    f32x4 acc[24];
    #pragma unroll
    for (int t = 0; t < 24; ++t) {
        const bf16x8 bfv = *(const bf16x8*)(kvsrc + t*256);
        f32x4 z4 = (f32x4){0.f,0.f,0.f,0.f};
        acc[t] = __builtin_amdgcn_mfma_f32_16x16x32_bf16(cqf, bfv, z4, 0, 0, 0);
    }

    const int rloc0 = wid*16 + fq*4;       // local row of first token
    const int tokj0 = tokA + fq*4;
    float s[4]  = {0.f,0.f,0.f,0.f};
    float s2[4] = {0.f,0.f,0.f,0.f};
    #pragma unroll
    for (int t = 0; t < 24; ++t) {
        const int hd = t*16 + fr;
        const float dvh = ds[hd];
        #pragma unroll
        for (int j = 0; j < 4; ++j) {
            const float vv = ldbfs(&yzs[(rloc0+j)*YPAD + hd]);
            const float y = fmaf(vv, dvh, acc[t][j]);
            acc[t][j] = y;
            s[j] += y;
            s2[j] = fmaf(y, y, s2[j]);
        }
    }
    #pragma unroll
    for (int j = 0; j < 4; ++j) {
        #pragma unroll
        for (int off = 8; off > 0; off >>= 1) {
            s[j]  += __shfl_xor(s[j],  off, 16);
            s2[j] += __shfl_xor(s2[j], off, 16);
        }
    }
    float mu[4], rs[4];
    #pragma unroll
    for (int j = 0; j < 4; ++j) {
        mu[j] = s[j] * (1.f/384.f);
        const float var = s2[j]*(1.f/384.f) - mu[j]*mu[j];
        rs[j] = rsqrtf(var + 1e-5f);
    }

    #pragma unroll
    for (int t = 0; t < 24; ++t) {
        const int hd = t*16 + fr;
        const float g = gs[hd], be = bs2[hd];
        const bf16* zsrc = z_bf + (size_t)(hd>>6)*TROW + (hd & 63);
        #pragma unroll
        for (int j = 0; j < 4; ++j) {
            const int tok = tokj0 + j;
            const float yn = fmaf((acc[t][j] - mu[j])*rs[j], g, be);
            const float zv = ldbf(zsrc + (size_t)tok*64);
            yzs[(rloc0+j)*YPAD + hd] = (short)f2bf(yn*zv);
        }
    }

    const short* yrow = &yzs[(wid*16 + fr)*YPAD];
    bf16x8 af[12];
    #pragma unroll
    for (int ks = 0; ks < 12; ++ks)
        af[ks] = *(const bf16x8*)(yrow + ks*32 + fq*8);

    f32x4 oacc[12];
    #pragma unroll
    for (int ni = 0; ni < 12; ++ni) oacc[ni] = (f32x4){0.f,0.f,0.f,0.f};

    #pragma unroll
    for (int ks = 0; ks < 12; ++ks) {
        #pragma unroll
        for (int ni = 0; ni < 12; ++ni) {
            const bf16x8 bw = *(const bf16x8*)((const short*)Wout_sh
                                + (size_t)((ni*12 + ks)*64 + lane)*8);
            oacc[ni] = __builtin_amdgcn_mfma_f32_16x16x32_bf16(af[ks], bw, oacc[ni], 0, 0, 0);
        }
    }

    #pragma unroll
    for (int ni = 0; ni < 12; ++ni) {
        const int n = ni*16 + fr;
        #pragma unroll
        for (int r = 0; r < 4; ++r)
            out[(size_t)(tokj0 + r)*DMODEL + n] = oacc[ni][r];
    }
}

// ---------------------------------------------------------------------------
extern "C" void kernel_launch(void* const* d_in, const int* in_sizes, int n_in,
                              void* d_out, int out_size, void* d_ws, size_t ws_size,
                              hipStream_t stream)
{
    const float* u      = (const float*)d_in[0];
    const float* t      = (const float*)d_in[1];
    const float* Win    = (const float*)d_in[2];
    const float* Wtin   = (const float*)d_in[3];
    const float* conv_w = (const float*)d_in[4];
    const float* conv_b = (const float*)d_in[5];
    const float* dt_b   = (const float*)d_in[6];
    const float* A_log  = (const float*)d_in[7];
    const float* Dv     = (const float*)d_in[8];
    const float* ln_g   = (const float*)d_in[9];
    const float* ln_bt  = (const float*)d_in[10];
    const float* W_out  = (const float*)d_in[11];
    float* out = (float*)d_out;

    char* p = (char*)d_ws;
    bf16* z_bf     = (bf16*)p;  p += (size_t)6*TROW*2;        // 50.3 MB (tiled)
    bf16* xbc_pre  = (bf16*)p;  p += (size_t)7*TROW*2;        // 58.7 MB (tiled; reused as kv partials)
    bf16* xbc_post = (bf16*)p;  p += (size_t)NTOK*CONVD*2;    // 54.5 MB
    float* cq_pre  = (float*)p; p += (size_t)NTOK*DST*4;      //  4.2 MB
    bf16* cq_bf    = (bf16*)p;  p += (size_t)NTOK*DST*2;      //  2.1 MB
    float* dA      = (float*)p; p += (size_t)NTOK*NH*4;       //  8.4 MB
    bf16* kvhl     = (bf16*)p;  p += (size_t)BN*2*6144*2;     //  98 KB
    bf16* Wsw      = (bf16*)p;  p += (size_t)832*DMODEL*2;    // 320 KB (swizzled frags)
    bf16* Wout_sh  = (bf16*)p;  p += (size_t)DMODEL*DINNER*2; // 148 KB (out B-frags)
    float* wtr     = (float*)p; p += (size_t)9*420*4;         // 15.1 KB

    float* kv_part = (float*)xbc_pre;   // xbc_pre dead after k_conv416

    k_prep<<<624, 256, 0, stream>>>(Win, W_out, conv_w, Wsw, Wout_sh, wtr);
    k_proj_mfma<<<dim3(NTOK/PM, 2), 512, 0, stream>>>(u, Wsw, dt_b, A_log, z_bf, xbc_pre, dA);
    k_tproj<<<NTOK/16, 256, 0, stream>>>(t, Wtin, cq_pre);
    k_conv416<<<NTOK/32, 416, 0, stream>>>(xbc_pre, wtr, conv_b, xbc_post);
    k_conv16<<<NTOK*16/256, 256, 0, stream>>>(cq_pre, conv_w, conv_b, cq_bf);
    k_kv<<<dim3(KVCHUNKS, BN), 512, 0, stream>>>(xbc_post, dA, kv_part);
    k_kvred<<<BN*6144/256, 256, 0, stream>>>(kv_part, kvhl);
    k_ynorm_out<<<NTOK/64, 256, 0, stream>>>(xbc_post, cq_bf, z_bf, kvhl,
                                             Dv, ln_g, ln_bt, Wout_sh, out);
}